// Round 3
// baseline (11027.196 us; speedup 1.0000x reference)
//
#include <hip/hip_runtime.h>

#define SEQ 999
#define HID 256
#define DTC 0.01f
#define CREG 104          // h2-cols kept in VGPRs per row (4 rows/thread)
#define CLDSU2 12         // 8-byte words per row in LDS (24 h2-cols)

typedef _Float16 h2 __attribute__((ext_vector_type(2)));

__device__ __forceinline__ h2 u2h(unsigned u){ return __builtin_bit_cast(h2, u); }
__device__ __forceinline__ unsigned h2u(h2 v){ return __builtin_bit_cast(unsigned, v); }

// v_dot2_f32_f16: dst/src2 = ACC (tied), src0 = h pair in SGPR, src1 = weight VGPR.
// The weight is declared as an in/out ("+v") so the allocator cannot rematerialize
// or fold it to a memory operand — it must live in a VGPR across the loop.
#define DOT(ACC, HS, WV) asm("v_dot2_f32_f16 %0, %2, %1, %0" : "+v"(ACC), "+v"(WV) : "s"(HS))
// LDS-sourced weight variant: no tie needed (re-read every step).
#define DOTL(ACC, HS, WU) asm("v_dot2_f32_f16 %0, %1, %2, %0" : "+v"(ACC) : "s"(HS), "v"(WU))

__device__ __forceinline__ unsigned sel4(uint4 v, int k){
  return k==0 ? v.x : k==1 ? v.y : k==2 ? v.z : v.w;   // k is compile-time post-unroll
}

__device__ __forceinline__ float softplusf(float x){
  return fmaxf(x, 0.f) + log1pf(__expf(-fabsf(x)));
}
__device__ __forceinline__ float sigmoidf(float x){
  return 1.f/(1.f + __expf(-x));
}
__device__ __forceinline__ float tanh_fast(float x){
  float e = __expf(-2.f*x);
  return (1.f - e)/(1.f + e);
}

// Weight conversion.
//  whh0/whh1 -> ROW-MAJOR f16:  wR[r*128 + c2] = (W[r][2c2], W[r][2c2+1])   (k_layer layout)
//  wih1      -> TRANSPOSED f16: wT[c2*1024 + r]                              (k_xw1 layout)
__global__ void k_convert(const float* __restrict__ whh0, const float* __restrict__ wih1,
                          const float* __restrict__ whh1,
                          const float* __restrict__ bih0, const float* __restrict__ bhh0,
                          const float* __restrict__ bih1, const float* __restrict__ bhh1,
                          h2* __restrict__ whh0R, h2* __restrict__ wih1T, h2* __restrict__ whh1R,
                          float* __restrict__ bs0, float* __restrict__ bs1){
  int o = blockIdx.x*256 + threadIdx.x;
  if (o < 131072){
    int r = o >> 7, c2 = o & 127;
    const float* s = whh0 + r*256 + 2*c2;
    whh0R[o] = h2{(_Float16)s[0], (_Float16)s[1]};
  } else if (o < 262144){
    int oo = o - 131072; int r = oo & 1023, c2 = oo >> 10;
    const float* s = wih1 + r*256 + 2*c2;
    wih1T[oo] = h2{(_Float16)s[0], (_Float16)s[1]};
  } else if (o < 393216){
    int oo = o - 262144; int r = oo >> 7, c2 = oo & 127;
    const float* s = whh1 + r*256 + 2*c2;
    whh1R[oo] = h2{(_Float16)s[0], (_Float16)s[1]};
  } else if (o < 394240){
    int r = o - 393216; bs0[r] = bih0[r] + bhh0[r];
  } else if (o < 395264){
    int r = o - 394240; bs1[r] = bih1[r] + bhh1[r];
  }
}

// One workgroup (256 threads, 1 CU) = one LSTM layer. Thread owns hidden unit `tid`
// and computes ALL FOUR gate rows {tid, 256+tid, 512+tid, 768+tid} = {i,f,g,o}:
// c,h are thread-private -> no gate exchange, 1 barrier/step.
// h distribution: one ds_read_b128 gathers all 256 f16 of h into lanes 0..31;
// v_readlane -> SGPR feeds v_dot2_f32_f16 (1 SGPR src is legal).
template<int MODE>  // 0: layer0 (x-projection inline), 1: layer1 (xw precomputed)
__global__ __launch_bounds__(256, 1)
void k_layer(const h2* __restrict__ wR, const float* __restrict__ wih0,
             const float* __restrict__ bs, const float* __restrict__ X,
             const float* __restrict__ xw1, _Float16* __restrict__ hOutHalf,
             float* __restrict__ hOutF32){
  __shared__ unsigned long long wlds[4][CLDSU2][256];   // 96 KB, 8B/lane stride (2-way = free)
  __shared__ _Float16 hbuf[2][256];                     // double-buffered h
  __shared__ float xlds[2*SEQ];                         // 8 KB (MODE 0)

  const int tid = threadIdx.x;

  unsigned wv0[CREG], wv1[CREG], wv2[CREG], wv3[CREG];
#pragma unroll
  for (int r=0;r<4;++r){
    unsigned* wv = r==0?wv0 : r==1?wv1 : r==2?wv2 : wv3;
    const uint4* src = (const uint4*)(wR + (r*256+tid)*128);
#pragma unroll
    for (int q=0;q<26;++q){       // cols 0..103 -> VGPRs
      uint4 v = src[q];
      wv[4*q+0]=v.x; wv[4*q+1]=v.y; wv[4*q+2]=v.z; wv[4*q+3]=v.w;
    }
#pragma unroll
    for (int qq=0;qq<6;++qq){     // cols 104..127 -> LDS
      uint4 v = src[26+qq];
      wlds[r][2*qq  ][tid] = ((unsigned long long)v.y << 32) | v.x;
      wlds[r][2*qq+1][tid] = ((unsigned long long)v.w << 32) | v.z;
    }
  }

  float bsr[4], wxa[4], wxb[4], nx[4];
  if (MODE == 0){
#pragma unroll
    for (int r=0;r<4;++r){
      bsr[r] = bs[r*256+tid];
      wxa[r] = wih0[(r*256+tid)*2 + 0];
      wxb[r] = wih0[(r*256+tid)*2 + 1];
    }
    for (int i=tid; i<2*SEQ; i+=256) xlds[i] = X[i];
  } else {
#pragma unroll
    for (int r=0;r<4;++r) nx[r] = xw1[r*256+tid];
  }

  float c = 0.f;
  uint4 hv = {0u,0u,0u,0u};      // h_{-1} = 0
  __syncthreads();

#pragma unroll 1
  for (int t=0; t<SEQ; ++t){
    float a0[4], a1[4];
    if (MODE == 0){
      float2 xv = *(const float2*)&xlds[2*t];
#pragma unroll
      for (int r=0;r<4;++r){
        a0[r] = fmaf(wxb[r], xv.y, fmaf(wxa[r], xv.x, bsr[r]));
        a1[r] = 0.f;
      }
    } else {
#pragma unroll
      for (int r=0;r<4;++r){ a0[r] = nx[r]; a1[r] = 0.f; }
      if (t+1 < SEQ){
#pragma unroll
        for (int r=0;r<4;++r) nx[r] = xw1[(t+1)*1024 + r*256 + tid];
      }
    }

    // Register-resident cols: readlane h2[j] -> SGPR, 4 gate-dots per j.
#pragma unroll
    for (int j=0;j<CREG;++j){
      unsigned hh = (unsigned)__builtin_amdgcn_readlane((int)sel4(hv, j&3), j>>2);
      if (j & 1){
        DOT(a1[0], hh, wv0[j]); DOT(a1[1], hh, wv1[j]);
        DOT(a1[2], hh, wv2[j]); DOT(a1[3], hh, wv3[j]);
      } else {
        DOT(a0[0], hh, wv0[j]); DOT(a0[1], hh, wv1[j]);
        DOT(a0[2], hh, wv2[j]); DOT(a0[3], hh, wv3[j]);
      }
    }
    // LDS-resident cols 104..127 (volatile so reads are NOT hoisted out of the loop).
#pragma unroll
    for (int q=0;q<CLDSU2;++q){
      const int ja = CREG + 2*q, jb = ja + 1;
      unsigned ha = (unsigned)__builtin_amdgcn_readlane((int)sel4(hv, ja&3), ja>>2);
      unsigned hb = (unsigned)__builtin_amdgcn_readlane((int)sel4(hv, jb&3), jb>>2);
      unsigned long long u0 = *(volatile unsigned long long*)&wlds[0][q][tid];
      unsigned long long u1 = *(volatile unsigned long long*)&wlds[1][q][tid];
      unsigned long long u2 = *(volatile unsigned long long*)&wlds[2][q][tid];
      unsigned long long u3 = *(volatile unsigned long long*)&wlds[3][q][tid];
      DOTL(a0[0], ha, (unsigned)u0); DOTL(a1[0], hb, (unsigned)(u0>>32));
      DOTL(a0[1], ha, (unsigned)u1); DOTL(a1[1], hb, (unsigned)(u1>>32));
      DOTL(a0[2], ha, (unsigned)u2); DOTL(a1[2], hb, (unsigned)(u2>>32));
      DOTL(a0[3], ha, (unsigned)u3); DOTL(a1[3], hb, (unsigned)(u3>>32));
    }

    float i_ = sigmoidf(a0[0] + a1[0]);
    float f_ = sigmoidf(a0[1] + a1[1]);
    float g_ = tanh_fast(a0[2] + a1[2]);
    float o_ = sigmoidf(a0[3] + a1[3]);
    c = fmaf(f_, c, i_*g_);
    float h = o_ * tanh_fast(c);

    hbuf[t&1][tid] = (_Float16)h;
    if (MODE == 0) hOutHalf[t*256 + tid] = (_Float16)h;
    else           hOutF32 [t*256 + tid] = h;
    __syncthreads();
    hv = *(const uint4*)((const char*)hbuf[t&1] + (tid&31)*16);   // gather new h
    // next iteration writes hbuf[(t+1)&1] -> no WAR hazard, single barrier suffices
  }
}

// xw1[t][r] = bs1[r] + Wih1[r,:] . h0[t,:]  -- parallel over t
__global__ __launch_bounds__(1024)
void k_xw1(const h2* __restrict__ wih1T, const float* __restrict__ bs1,
           const h2* __restrict__ h0, float* __restrict__ xw1){
  const int tid = threadIdx.x;
#pragma unroll 1
  for (int tt=0; tt<8; ++tt){
    int t = blockIdx.x*8 + tt;
    if (t >= SEQ) return;
    const uint4* hv4 = (const uint4*)(h0 + t*128);
    float acc = bs1[tid];
#pragma unroll
    for (int q=0;q<32;++q){
      uint4 hv = hv4[q];
      acc = __builtin_amdgcn_fdot2(u2h(hv.x), u2h(h2u(wih1T[(4*q+0)*1024 + tid])), acc, false);
      acc = __builtin_amdgcn_fdot2(u2h(hv.y), u2h(h2u(wih1T[(4*q+1)*1024 + tid])), acc, false);
      acc = __builtin_amdgcn_fdot2(u2h(hv.z), u2h(h2u(wih1T[(4*q+2)*1024 + tid])), acc, false);
      acc = __builtin_amdgcn_fdot2(u2h(hv.w), u2h(h2u(wih1T[(4*q+3)*1024 + tid])), acc, false);
    }
    xw1[t*1024 + tid] = acc;
  }
}

// z1[j] = softplus(W1[j,:] . h1_flat + b1[j]); one block per output row, 262 MB streamed once.
__global__ __launch_bounds__(256)
void k_w1(const float* __restrict__ W1, const float* __restrict__ b1,
          const float* __restrict__ h1f, float* __restrict__ z1){
  __shared__ float red[256];
  const int j = blockIdx.x, tid = threadIdx.x;
  const float4* w4 = (const float4*)(W1 + (size_t)j * (SEQ*HID));
  const float4* h4 = (const float4*)h1f;
  float acc = 0.f;
  for (int q = tid; q < (SEQ*HID/4); q += 256){
    float4 w = w4[q], h = h4[q];
    acc = fmaf(w.x, h.x, acc); acc = fmaf(w.y, h.y, acc);
    acc = fmaf(w.z, h.z, acc); acc = fmaf(w.w, h.w, acc);
  }
  red[tid] = acc; __syncthreads();
  for (int s=128; s>0; s>>=1){
    if (tid < s) red[tid] += red[tid+s];
    __syncthreads();
  }
  if (tid == 0) z1[j] = softplusf(red[0] + b1[j]);
}

// MLP tail + 999-step explicit Euler (serial, 1 thread)
__global__ __launch_bounds__(128)
void k_head(const float* __restrict__ W2, const float* __restrict__ b2,
            const float* __restrict__ W3, const float* __restrict__ b3,
            const float* __restrict__ z1, const float* __restrict__ data,
            float* __restrict__ out){
  __shared__ float z1s[256], z2s[128], ab[4];
  const int tid = threadIdx.x;
  z1s[tid] = z1[tid]; z1s[tid+128] = z1[tid+128];
  __syncthreads();
  float acc = b2[tid];
  for (int k=0;k<256;++k) acc = fmaf(W2[tid*256+k], z1s[k], acc);
  z2s[tid] = softplusf(acc);
  __syncthreads();
  if (tid < 4){
    float a = b3[tid];
    for (int k=0;k<128;++k) a = fmaf(W3[tid*128+k], z2s[k], a);
    ab[tid] = a;
  }
  __syncthreads();
  if (tid == 0){
    float a = ab[0], b = ab[1], cc = ab[2], d = ab[3];
    float R = data[0], J = data[1];
#pragma unroll 1
    for (int t=0;t<SEQ;++t){
      float RJ = R*J;
      float Rn = R + DTC*(a*R - b*RJ);
      float Jn = J + DTC*(d*RJ - cc*J);
      out[2*t] = Rn; out[2*t+1] = Jn;
      R = Rn; J = Jn;
    }
  }
}

extern "C" void kernel_launch(void* const* d_in, const int* in_sizes, int n_in,
                              void* d_out, int out_size, void* d_ws, size_t ws_size,
                              hipStream_t stream){
  const float* X    = (const float*)d_in[0];
  const float* data = (const float*)d_in[1];
  const float* Wih0 = (const float*)d_in[2];
  const float* Whh0 = (const float*)d_in[3];
  const float* bih0 = (const float*)d_in[4];
  const float* bhh0 = (const float*)d_in[5];
  const float* Wih1 = (const float*)d_in[6];
  const float* Whh1 = (const float*)d_in[7];
  const float* bih1 = (const float*)d_in[8];
  const float* bhh1 = (const float*)d_in[9];
  const float* W1   = (const float*)d_in[10];
  const float* b1   = (const float*)d_in[11];
  const float* W2   = (const float*)d_in[12];
  const float* b2   = (const float*)d_in[13];
  const float* W3   = (const float*)d_in[14];
  const float* b3   = (const float*)d_in[15];
  float* out = (float*)d_out;

  char* w = (char*)d_ws;
  h2*       whh0R = (h2*)(w + 0);              // 512 KB (row-major f16)
  h2*       wih1T = (h2*)(w + 524288);         // 512 KB (transposed f16)
  h2*       whh1R = (h2*)(w + 1048576);        // 512 KB (row-major f16)
  float*    bs0   = (float*)(w + 1572864);     // 4 KB
  float*    bs1   = (float*)(w + 1576960);     // 4 KB
  _Float16* h0h   = (_Float16*)(w + 1581056);  // 999*256*2 = 511,488 B
  float*    xw1   = (float*)(w + 2097152);     // 999*1024*4 = 4,091,904 B
  float*    h1f   = (float*)(w + 6189056);     // 999*256*4 = 1,022,976 B
  float*    z1    = (float*)(w + 7212032);     // 1 KB   (total ~7.2 MB)

  k_convert<<<1544, 256, 0, stream>>>(Whh0, Wih1, Whh1, bih0, bhh0, bih1, bhh1,
                                      whh0R, wih1T, whh1R, bs0, bs1);
  k_layer<0><<<1, 256, 0, stream>>>(whh0R, Wih0, bs0, X, nullptr, h0h, nullptr);
  k_xw1<<<125, 1024, 0, stream>>>(wih1T, bs1, (const h2*)h0h, xw1);
  k_layer<1><<<1, 256, 0, stream>>>(whh1R, nullptr, bs1, nullptr, xw1, nullptr, h1f);
  k_w1<<<256, 256, 0, stream>>>(W1, b1, h1f, z1);
  k_head<<<1, 128, 0, stream>>>(W2, b2, W3, b3, z1, data, out);
}